// Round 10
// baseline (422.000 us; speedup 1.0000x reference)
//
#include <hip/hip_runtime.h>
#include <hip/hip_bf16.h>
#include <math.h>

#define N_NODES 50000
#define N_EDGES 600000
#define HDIM    128
#define NLAYERS 4
#define NGRAPH  256
#define SCAN_BLOCKS 196   // 196*256 = 50176 >= N_NODES

typedef _Float16 half8 __attribute__((ext_vector_type(8)));   // 8 x fp16 (4 VGPRs)
typedef __attribute__((ext_vector_type(4))) float float4v;    // MFMA acc
typedef float floatx2 __attribute__((ext_vector_type(2)));
typedef unsigned short ushort_t;
typedef unsigned int uint_t;
typedef unsigned char uchar_t;
typedef unsigned long long ulong_t;

__device__ __forceinline__ float h2f(ushort_t u) {
    union { ushort_t u; _Float16 h; } x; x.u = u; return (float)x.h;
}
__device__ __forceinline__ ushort_t f2h(float f) {
    union { ushort_t u; _Float16 h; } x; x.h = (_Float16)f; return x.u;
}
__device__ __forceinline__ uint_t pkrtz(float a, float b) {
    typedef __fp16 fp16x2 __attribute__((ext_vector_type(2)));
    fp16x2 h = __builtin_amdgcn_cvt_pkrtz(a, b);
    union { fp16x2 h; uint_t u; } x; x.h = h; return x.u;
}

// ------------------------------------------------------------------
// fp16 MFMA GEMM, B-stationary. R10: TWO-DEEP A register prefetch
// (a0/a1/a2): tile t+2G's loads issue while tile t computes, giving
// ~2 iterations (~400cy) of latency cover for the ~250-300cy L2-hit
// A loads, vs ~180cy with 1-deep (R7/R9). No grid / launch_bounds
// change (R8 showed VGPR clamp + grid doubling both regress).
// +16 VGPR, stays in the 3-waves/SIMD band.
//
// PANEL PERMUTATION: panel slot (colbase + c*16 + l16) holds the weight
// column for MEMORY column (colbase + 4*l16 + c); lane's acc[0..3] are
// 4 adjacent memory columns -> packed stores.
//
// mode 0 (embed, NC=128): write h16 fp16 (uint2)
// mode 1 (layer, NC=512):
//   memory cols   0..255 -> seed16[row][256] fp16 (gr', r) pairs (uint2)
//   memory cols 256..511 -> gsv8[row][256B] fp8 e4m3 (gs', sv) pairs
//   gr' and gs' are pre-scaled by -log2e at panel build.
// ------------------------------------------------------------------
__device__ __forceinline__ void load_a_tile(half8 (&a)[4],
    const ushort_t* __restrict__ A16, const float* __restrict__ Af32,
    int arow, int quad)
{
    if (Af32) {
        const float* ap = Af32 + (size_t)arow * 128 + quad * 8;
#pragma unroll
        for (int k0 = 0; k0 < 4; k0++) {
            float4 f0 = *(const float4*)(ap + k0 * 32);
            float4 f1 = *(const float4*)(ap + k0 * 32 + 4);
            half8 v;
            v[0]=(_Float16)f0.x; v[1]=(_Float16)f0.y; v[2]=(_Float16)f0.z; v[3]=(_Float16)f0.w;
            v[4]=(_Float16)f1.x; v[5]=(_Float16)f1.y; v[6]=(_Float16)f1.z; v[7]=(_Float16)f1.w;
            a[k0] = v;
        }
    } else {
        const ushort_t* ap = A16 + (size_t)arow * 128 + quad * 8;
#pragma unroll
        for (int k0 = 0; k0 < 4; k0++) a[k0] = *(const half8*)(ap + k0 * 32);
    }
}

__global__ __launch_bounds__(256) void mfma_gemm_f16(
    const ushort_t* __restrict__ A16, const float* __restrict__ Af32,
    const ushort_t* __restrict__ Bt,
    const float* __restrict__ bias, int M, int mode,
    ushort_t* __restrict__ h16,
    ushort_t* __restrict__ seed16, uchar_t* __restrict__ gsv8)
{
    const int tid  = threadIdx.x;
    const int wave = tid >> 6, lane = tid & 63;
    const int quad = lane >> 4, l16 = lane & 15;
    const int nwaves = blockDim.x >> 6;
    const int colbase = (blockIdx.y * nwaves + wave) * 64;   // 64 cols per wave

    // B fragments: resident for the whole kernel (16 x 16B loads)
    half8 bf[4][4];
#pragma unroll
    for (int c = 0; c < 4; c++)
#pragma unroll
        for (int k0 = 0; k0 < 4; k0++)
            bf[c][k0] = *(const half8*)(Bt + (size_t)(colbase + c * 16 + l16) * 128
                                           + k0 * 32 + quad * 8);

    // bias for this lane's 4 adjacent memory cols
    const int mcol = colbase + 4 * l16;
    const float4 bv = *(const float4*)(bias + mcol);

    const int ntiles = (M + 15) >> 4;
    const int G = gridDim.x;
    int tile = blockIdx.x;
    if (tile >= ntiles) return;

    half8 a0[4], a1[4], a2[4];
    {
        int r0 = tile * 16 + l16;          if (r0 >= M) r0 = M - 1;
        load_a_tile(a0, A16, Af32, r0, quad);
        if (tile + G < ntiles) {
            int r1 = (tile + G) * 16 + l16; if (r1 >= M) r1 = M - 1;
            load_a_tile(a1, A16, Af32, r1, quad);
        }
    }

    while (true) {
        const int nt2 = tile + 2 * G;
        if (nt2 < ntiles) {
            int r2 = nt2 * 16 + l16; if (r2 >= M) r2 = M - 1;
            load_a_tile(a2, A16, Af32, r2, quad);
        }

        float4v acc[4];
        float4v z = {0.f, 0.f, 0.f, 0.f};
#pragma unroll
        for (int c = 0; c < 4; c++) acc[c] = z;
#pragma unroll
        for (int k0 = 0; k0 < 4; k0++)
#pragma unroll
            for (int c = 0; c < 4; c++)
                acc[c] = __builtin_amdgcn_mfma_f32_16x16x32_f16(a0[k0], bf[c][k0], acc[c], 0, 0, 0);

        // epilogue — C/D: col=lane&15, row=quad*4+reg. acc[c][r] = memory col mcol+c.
        // For mode 1 the branch below is WAVE-UNIFORM (colbase is a multiple of 64).
        const int rowb = tile * 16 + quad * 4;
#pragma unroll
        for (int r = 0; r < 4; r++) {
            const int row = rowb + r;
            if (row < M) {
                const float v0 = acc[0][r] + bv.x;
                const float v1 = acc[1][r] + bv.y;
                const float v2 = acc[2][r] + bv.z;
                const float v3 = acc[3][r] + bv.w;
                if (mode == 0) {
                    uint2 u; u.x = pkrtz(v0, v1); u.y = pkrtz(v2, v3);
                    *(uint2*)(h16 + (size_t)row * 128 + mcol) = u;
                } else if (mcol < 256) {
                    uint2 u; u.x = pkrtz(v0, v1); u.y = pkrtz(v2, v3);
                    *(uint2*)(seed16 + (size_t)row * 256 + mcol) = u;
                } else {
                    // pack 4 values (gs0,sv0,gs1,sv1) as fp8 e4m3 into one dword
                    uint_t pk8 = (uint_t)__builtin_amdgcn_cvt_pk_fp8_f32(v0, v1, 0, false);
                    pk8 = (uint_t)__builtin_amdgcn_cvt_pk_fp8_f32(v2, v3, (int)pk8, true);
                    *(uint_t*)(gsv8 + (size_t)row * 256 + (mcol - 256)) = pk8;
                }
            }
        }

        const int nt = tile + G;
        if (nt >= ntiles) break;
#pragma unroll
        for (int k0 = 0; k0 < 4; k0++) { a0[k0] = a1[k0]; a1[k0] = a2[k0]; }
        tile = nt;
    }
}

// ------------------------------------------------------------------
// Weight panels (transposed, fp16), with the lane-packing permutation:
// panel slot p (within a 64-col group) = c*16 + l16 feeds memory col
// m = 4*l16 + c.
// ------------------------------------------------------------------
__global__ void build_wembed(const float* __restrict__ W, ushort_t* __restrict__ Wt)
{
    int t = blockIdx.x * blockDim.x + threadIdx.x;   // t = p*128 + k
    if (t >= 128 * 128) return;
    int p = t >> 7, k = t & 127;
    int w = p >> 6, rem = p & 63, c = rem >> 4, l16 = rem & 15;
    int m = w * 64 + 4 * l16 + c;
    Wt[t] = f2h(W[k * 128 + m]);
}

// Layer panel. Memory col m:
//   m in [0,256):   even -> gr' = -log2e*Wg[l][k][m/2], bias -log2e*bg
//                   odd  -> r  = Wr[l][k][m/2],         bias br
//   m in [256,512): even -> gs' = -log2e*Wg[l][128+k][(m-256)/2], bias 0
//                   odd  -> sv = Ws[l][k][(m-256)/2],   bias bs
// bcat is indexed by MEMORY col m.
__global__ void build_wcat(const float* __restrict__ Wg, const float* __restrict__ Ws,
                           const float* __restrict__ Wr, const float* __restrict__ bg,
                           const float* __restrict__ bs, const float* __restrict__ br,
                           ushort_t* __restrict__ Wt, float* __restrict__ bcat)
{
    int t = blockIdx.x * blockDim.x + threadIdx.x;   // t = ((l*512)+p)*128 + k
    if (t >= NLAYERS * 512 * 128) return;
    int l = t >> 16;
    int rm = t & 65535;
    int p = rm >> 7;
    int k = rm & 127;
    int w = p >> 6, rem = p & 63, c = rem >> 4, l16 = rem & 15;
    int m = w * 64 + 4 * l16 + c;
    const float NL2E = -1.44269504088896f;
    float v, b;
    if (m < 256) {
        int j = m >> 1;
        if ((m & 1) == 0) { v = NL2E * Wg[l * 32768 + k * 128 + j]; b = NL2E * bg[l * 128 + j]; }
        else              { v = Wr[l * 16384 + k * 128 + j];        b = br[l * 128 + j]; }
    } else {
        int j = (m - 256) >> 1;
        if ((m & 1) == 0) { v = NL2E * Wg[l * 32768 + (128 + k) * 128 + j]; b = 0.f; }
        else              { v = Ws[l * 16384 + k * 128 + j];               b = bs[l * 128 + j]; }
    }
    Wt[t] = f2h(v);
    if (k == 0) bcat[l * 512 + m] = b;
}

// ------------------------------------------------------------------
// CSR build: histogram -> two-level scan -> scatter
// ------------------------------------------------------------------
__global__ __launch_bounds__(256) void hist_kernel(const int* __restrict__ ei,
                                                   int* __restrict__ cnt)
{
    int e = blockIdx.x * blockDim.x + threadIdx.x;
    if (e < N_EDGES) atomicAdd(&cnt[ei[N_EDGES + e]], 1);
}

__global__ __launch_bounds__(256) void scan_partial(const int* __restrict__ cnt,
                                                    int* __restrict__ part)
{
    __shared__ int ws[4];
    int tid = threadIdx.x, lane = tid & 63, wid = tid >> 6;
    int i = blockIdx.x * 256 + tid;
    int v = (i < N_NODES) ? cnt[i] : 0;
    int x = v;
#pragma unroll
    for (int ofs = 32; ofs > 0; ofs >>= 1) x += __shfl_down(x, ofs);
    if (lane == 0) ws[wid] = x;
    __syncthreads();
    if (tid == 0) part[blockIdx.x] = ws[0] + ws[1] + ws[2] + ws[3];
}

__global__ __launch_bounds__(256) void scan_root(const int* __restrict__ part,
                                                 int* __restrict__ partpre)
{
    __shared__ int ws[4];
    int tid = threadIdx.x, lane = tid & 63, wid = tid >> 6;
    int v = (tid < SCAN_BLOCKS) ? part[tid] : 0;
    int x = v;
#pragma unroll
    for (int ofs = 1; ofs < 64; ofs <<= 1) {
        int y = __shfl_up(x, ofs);
        if (lane >= ofs) x += y;
    }
    if (lane == 63) ws[wid] = x;
    __syncthreads();
    int add = 0;
    for (int w = 0; w < wid; w++) add += ws[w];
    if (tid < SCAN_BLOCKS) partpre[tid] = add + x - v;   // exclusive
}

__global__ __launch_bounds__(256) void scan_write(const int* __restrict__ cnt,
                                                  const int* __restrict__ partpre,
                                                  int* __restrict__ off)
{
    __shared__ int ws[4];
    int tid = threadIdx.x, lane = tid & 63, wid = tid >> 6;
    int i = blockIdx.x * 256 + tid;
    int v = (i < N_NODES) ? cnt[i] : 0;
    int x = v;
#pragma unroll
    for (int ofs = 1; ofs < 64; ofs <<= 1) {
        int y = __shfl_up(x, ofs);
        if (lane >= ofs) x += y;
    }
    if (lane == 63) ws[wid] = x;
    __syncthreads();
    int add = partpre[blockIdx.x];
    for (int w = 0; w < wid; w++) add += ws[w];
    if (i < N_NODES) off[i + 1] = add + x;
    if (i == 0) off[0] = 0;
}

__global__ __launch_bounds__(256) void scatter_kernel(const int* __restrict__ ei,
                                                      const int* __restrict__ off,
                                                      int* __restrict__ cur,
                                                      int* __restrict__ csr_send)
{
    int e = blockIdx.x * blockDim.x + threadIdx.x;
    if (e >= N_EDGES) return;
    int rec = ei[N_EDGES + e];
    int pos = off[rec] + atomicAdd(&cur[rec], 1);
    csr_send[pos] = ei[e];
}

// ------------------------------------------------------------------
// Node-centric aggregation + fused residual update (R9 champion,
// UNCHANGED — serves as control this round): 1 wave/node, 8/4/2/1
// batched gather, fp8 e4m3 payload (256B/edge), fp16 seed,
// LDS pre-reduce pool on last layer.
// ------------------------------------------------------------------
__device__ __forceinline__ float sig_msg(float gpre, float sv) {
    // gpre = gr' + gs' (pre-scaled by -log2e): sigmoid = rcp(1+exp2(gpre))
    float e = __builtin_amdgcn_exp2f(gpre);
    return sv * __builtin_amdgcn_rcpf(1.f + e);
}

__global__ __launch_bounds__(256) void agg_kernel(
    const int* __restrict__ off, const int* __restrict__ csr_send,
    const ushort_t* __restrict__ seed16, const uchar_t* __restrict__ gsv8,
    ushort_t* __restrict__ h16,
    float* __restrict__ hagg, const int* __restrict__ batch)
{
    __shared__ float lred[4][128];
    __shared__ int lg[4];

    const int wave = threadIdx.x >> 6, lane = threadIdx.x & 63;
    const int n = blockIdx.x * 4 + wave;
    // N_NODES % 4 == 0, grid = N/4: every wave valid; no divergence
    // around __syncthreads below.

    ulong_t seed = *(const ulong_t*)(seed16 + (size_t)n * 256 + 4 * lane);
    // hoist the residual read so it's in flight under the gather loop
    uint_t hp = *(const uint_t*)(h16 + (size_t)n * 128 + 2 * lane);

    float gr0  = h2f((ushort_t)(seed & 0xffff));
    float acc0 = h2f((ushort_t)((seed >> 16) & 0xffff));
    float gr1  = h2f((ushort_t)((seed >> 32) & 0xffff));
    float acc1 = h2f((ushort_t)(seed >> 48));

    const uchar_t* gbase = gsv8 + 4 * lane;

    int p  = off[n];
    int p1 = off[n + 1];
    for (; p + 7 < p1; p += 8) {
        int s[8];
#pragma unroll
        for (int u = 0; u < 8; u++) s[u] = csr_send[p + u];
        uint_t q[8];
#pragma unroll
        for (int u = 0; u < 8; u++)
            q[u] = *(const uint_t*)(gbase + (size_t)s[u] * 256);
#pragma unroll
        for (int u = 0; u < 8; u++) {
            floatx2 a = __builtin_amdgcn_cvt_pk_f32_fp8(q[u], false);  // (gs0, sv0)
            floatx2 b = __builtin_amdgcn_cvt_pk_f32_fp8(q[u], true);   // (gs1, sv1)
            acc0 += sig_msg(gr0 + a.x, a.y);
            acc1 += sig_msg(gr1 + b.x, b.y);
        }
    }
    if (p + 3 < p1) {   // 4-wide tail batch (runs at most once)
        int s[4];
#pragma unroll
        for (int u = 0; u < 4; u++) s[u] = csr_send[p + u];
        uint_t q[4];
#pragma unroll
        for (int u = 0; u < 4; u++)
            q[u] = *(const uint_t*)(gbase + (size_t)s[u] * 256);
#pragma unroll
        for (int u = 0; u < 4; u++) {
            floatx2 a = __builtin_amdgcn_cvt_pk_f32_fp8(q[u], false);
            floatx2 b = __builtin_amdgcn_cvt_pk_f32_fp8(q[u], true);
            acc0 += sig_msg(gr0 + a.x, a.y);
            acc1 += sig_msg(gr1 + b.x, b.y);
        }
        p += 4;
    }
    if (p + 1 < p1) {   // 2-wide (runs at most once)
        int sa = csr_send[p], sb = csr_send[p + 1];
        uint_t qa = *(const uint_t*)(gbase + (size_t)sa * 256);
        uint_t qb = *(const uint_t*)(gbase + (size_t)sb * 256);
        floatx2 a0 = __builtin_amdgcn_cvt_pk_f32_fp8(qa, false);
        floatx2 a1 = __builtin_amdgcn_cvt_pk_f32_fp8(qa, true);
        floatx2 b0 = __builtin_amdgcn_cvt_pk_f32_fp8(qb, false);
        floatx2 b1 = __builtin_amdgcn_cvt_pk_f32_fp8(qb, true);
        acc0 += sig_msg(gr0 + a0.x, a0.y); acc1 += sig_msg(gr1 + a1.x, a1.y);
        acc0 += sig_msg(gr0 + b0.x, b0.y); acc1 += sig_msg(gr1 + b1.x, b1.y);
        p += 2;
    }
    if (p < p1) {
        int sa = csr_send[p];
        uint_t qa = *(const uint_t*)(gbase + (size_t)sa * 256);
        floatx2 a0 = __builtin_amdgcn_cvt_pk_f32_fp8(qa, false);
        floatx2 a1 = __builtin_amdgcn_cvt_pk_f32_fp8(qa, true);
        acc0 += sig_msg(gr0 + a0.x, a0.y); acc1 += sig_msg(gr1 + a1.x, a1.y);
    }

    float hx = h2f((ushort_t)(hp & 0xffff)) + fmaxf(acc0, 0.f);
    float hy = h2f((ushort_t)(hp >> 16))   + fmaxf(acc1, 0.f);

    if (hagg) {
        // fused global_add_pool with LDS block pre-reduction
        lred[wave][2 * lane]     = hx;
        lred[wave][2 * lane + 1] = hy;
        if (lane == 0) lg[wave] = batch[n];
        __syncthreads();
        if (wave == 0) {
            int gcur = lg[0];
            float a0 = lred[0][2 * lane], a1 = lred[0][2 * lane + 1];
#pragma unroll
            for (int w = 1; w < 4; w++) {
                const int gw = lg[w];
                const float b0 = lred[w][2 * lane], b1 = lred[w][2 * lane + 1];
                if (gw == gcur) { a0 += b0; a1 += b1; }
                else {
                    unsafeAtomicAdd(&hagg[(size_t)gcur * 128 + 2 * lane],     a0);
                    unsafeAtomicAdd(&hagg[(size_t)gcur * 128 + 2 * lane + 1], a1);
                    gcur = gw; a0 = b0; a1 = b1;
                }
            }
            unsafeAtomicAdd(&hagg[(size_t)gcur * 128 + 2 * lane],     a0);
            unsafeAtomicAdd(&hagg[(size_t)gcur * 128 + 2 * lane + 1], a1);
        }
    } else {
        *(uint_t*)(h16 + (size_t)n * 128 + 2 * lane) = pkrtz(hx, hy);
    }
}

// ------------------------------------------------------------------
// Head: out[g] = relu(hagg[g] @ W1 + b1) @ W2 + b2
// ------------------------------------------------------------------
__global__ __launch_bounds__(64) void head_kernel(
    const float* __restrict__ hagg, const float* __restrict__ W1,
    const float* __restrict__ b1, const float* __restrict__ W2,
    const float* __restrict__ b2, float* __restrict__ out)
{
    int g = blockIdx.x;
    int j = threadIdx.x;
    float acc = b1[j];
    for (int k = 0; k < 128; k++)
        acc += hagg[(size_t)g * 128 + k] * W1[k * 64 + j];
    float val = fmaxf(acc, 0.f) * W2[j];
#pragma unroll
    for (int off = 32; off > 0; off >>= 1)
        val += __shfl_down(val, off);
    if (j == 0) out[g] = val + b2[0];
}

// ------------------------------------------------------------------
extern "C" void kernel_launch(void* const* d_in, const int* in_sizes, int n_in,
                              void* d_out, int out_size, void* d_ws, size_t ws_size,
                              hipStream_t stream) {
    const float* h_in    = (const float*)d_in[0];
    const int*   ei      = (const int*)d_in[1];
    const int*   batch   = (const int*)d_in[2];
    const float* W_embed = (const float*)d_in[3];
    const float* b_embed = (const float*)d_in[4];
    const float* Wg      = (const float*)d_in[5];
    const float* bg      = (const float*)d_in[6];
    const float* Ws      = (const float*)d_in[7];
    const float* bs      = (const float*)d_in[8];
    const float* Wr      = (const float*)d_in[9];
    const float* br      = (const float*)d_in[10];
    const float* W1      = (const float*)d_in[11];
    const float* b1      = (const float*)d_in[12];
    const float* W2      = (const float*)d_in[13];
    const float* b2      = (const float*)d_in[14];
    float* out = (float*)d_out;

    // workspace layout (fp32, then fp16, then fp8, then ints)
    float* ws = (float*)d_ws;
    float*    hagg  = ws;                                    // G*128 f32
    float*    bcat  = hagg + NGRAPH * 128;                   // 4*512 f32
    ushort_t* h16   = (ushort_t*)(bcat + NLAYERS * 512);     // N*128 fp16
    ushort_t* seed16= h16 + (size_t)N_NODES * 128;           // N*256 fp16 (gr',r)
    ushort_t* wet   = seed16 + (size_t)N_NODES * 256;        // 128*128
    ushort_t* wct   = wet + 128 * 128;                       // 4*512*128
    uchar_t*  gsv8  = (uchar_t*)(wct + NLAYERS * 512 * 128); // N*256 fp8 (gs',sv)
    int* cnt      = (int*)(gsv8 + (size_t)N_NODES * 256);    // N
    int* cur      = cnt + N_NODES;                           // N
    int* off      = cur + N_NODES;                           // N+1
    int* csr_send = off + N_NODES + 1;                       // E
    int* part     = csr_send + N_EDGES;                      // SCAN_BLOCKS
    int* partpre  = part + SCAN_BLOCKS;                      // SCAN_BLOCKS

    // CSR build
    hipMemsetAsync(cnt, 0, (size_t)2 * N_NODES * sizeof(int), stream);
    hipMemsetAsync(hagg, 0, (size_t)NGRAPH * 128 * sizeof(float), stream);
    hist_kernel<<<(N_EDGES + 255) / 256, 256, 0, stream>>>(ei, cnt);
    scan_partial<<<SCAN_BLOCKS, 256, 0, stream>>>(cnt, part);
    scan_root<<<1, 256, 0, stream>>>(part, partpre);
    scan_write<<<SCAN_BLOCKS, 256, 0, stream>>>(cnt, partpre, off);
    scatter_kernel<<<(N_EDGES + 255) / 256, 256, 0, stream>>>(ei, off, cur, csr_send);

    // weight panels
    build_wembed<<<(128 * 128 + 255) / 256, 256, 0, stream>>>(W_embed, wet);
    build_wcat<<<(NLAYERS * 512 * 128 + 255) / 256, 256, 0, stream>>>(
        Wg, Ws, Wr, bg, bs, br, wct, bcat);

    // embed: h16 = fp16(h_in @ W_embed + b_embed)  (reads fp32 A directly)
    {
        dim3 grid(768, 1);
        mfma_gemm_f16<<<grid, 128, 0, stream>>>(nullptr, h_in, wet, b_embed,
                                                N_NODES, 0, h16, nullptr, nullptr);
    }

    for (int l = 0; l < NLAYERS; l++) {
        dim3 grid(384, 2);
        mfma_gemm_f16<<<grid, 256, 0, stream>>>(h16, nullptr,
                                                wct + (size_t)l * 512 * 128,
                                                bcat + l * 512, N_NODES, 1,
                                                nullptr, seed16, gsv8);
        const bool last = (l == NLAYERS - 1);
        agg_kernel<<<N_NODES / 4, 256, 0, stream>>>(
            off, csr_send, seed16, gsv8, h16,
            last ? hagg : nullptr, last ? batch : nullptr);
    }

    head_kernel<<<NGRAPH, 64, 0, stream>>>(hagg, W1, b1, W2, b2, out);
}

// Round 11
// 411.492 us; speedup vs baseline: 1.0255x; 1.0255x over previous
//
#include <hip/hip_runtime.h>
#include <hip/hip_bf16.h>
#include <math.h>

#define N_NODES 50000
#define N_EDGES 600000
#define HDIM    128
#define NLAYERS 4
#define NGRAPH  256
#define SCAN_BLOCKS 196   // 196*256 = 50176 >= N_NODES

typedef _Float16 half8 __attribute__((ext_vector_type(8)));   // 8 x fp16 (4 VGPRs)
typedef __attribute__((ext_vector_type(4))) float float4v;    // MFMA acc
typedef float floatx2 __attribute__((ext_vector_type(2)));
typedef unsigned short ushort_t;
typedef unsigned int uint_t;
typedef unsigned char uchar_t;
typedef unsigned long long ulong_t;

__device__ __forceinline__ float h2f(ushort_t u) {
    union { ushort_t u; _Float16 h; } x; x.u = u; return (float)x.h;
}
__device__ __forceinline__ ushort_t f2h(float f) {
    union { ushort_t u; _Float16 h; } x; x.h = (_Float16)f; return x.u;
}
__device__ __forceinline__ uint_t pkrtz(float a, float b) {
    typedef __fp16 fp16x2 __attribute__((ext_vector_type(2)));
    fp16x2 h = __builtin_amdgcn_cvt_pkrtz(a, b);
    union { fp16x2 h; uint_t u; } x; x.h = h; return x.u;
}

// ------------------------------------------------------------------
// fp16 MFMA GEMM, B-stationary, A register-double-buffered (1-deep —
// the R9 champion config; R10's 2-deep prefetch was null/slightly
// negative, R8's occupancy push regressed: the GEMMs are at their
// structural floor for this shape).
//
// PANEL PERMUTATION: panel slot (colbase + c*16 + l16) holds the weight
// column for MEMORY column (colbase + 4*l16 + c); lane's acc[0..3] are
// 4 adjacent memory columns -> packed stores.
//
// mode 0 (embed, NC=128): write h16 fp16 (uint2)
// mode 1 (layer, NC=512):
//   memory cols   0..255 -> seed16[row][256] fp16 (gr', r) pairs (uint2)
//   memory cols 256..511 -> gsv8[row][256B] fp8 e4m3 (gs', sv) pairs
//   gr' and gs' are pre-scaled by -log2e at panel build.
// ------------------------------------------------------------------
__global__ __launch_bounds__(256) void mfma_gemm_f16(
    const ushort_t* __restrict__ A16, const float* __restrict__ Af32,
    const ushort_t* __restrict__ Bt,
    const float* __restrict__ bias, int M, int mode,
    ushort_t* __restrict__ h16,
    ushort_t* __restrict__ seed16, uchar_t* __restrict__ gsv8)
{
    const int tid  = threadIdx.x;
    const int wave = tid >> 6, lane = tid & 63;
    const int quad = lane >> 4, l16 = lane & 15;
    const int nwaves = blockDim.x >> 6;
    const int colbase = (blockIdx.y * nwaves + wave) * 64;   // 64 cols per wave

    // B fragments: resident for the whole kernel (16 x 16B loads)
    half8 bf[4][4];
#pragma unroll
    for (int c = 0; c < 4; c++)
#pragma unroll
        for (int k0 = 0; k0 < 4; k0++)
            bf[c][k0] = *(const half8*)(Bt + (size_t)(colbase + c * 16 + l16) * 128
                                           + k0 * 32 + quad * 8);

    // bias for this lane's 4 adjacent memory cols
    const int mcol = colbase + 4 * l16;
    const float4 bv = *(const float4*)(bias + mcol);

    const int ntiles = (M + 15) >> 4;
    int tile = blockIdx.x;
    if (tile >= ntiles) return;

    half8 acur[4], anext[4];
    {
        int arow = tile * 16 + l16;
        if (arow >= M) arow = M - 1;
        if (Af32) {
            const float* ap = Af32 + (size_t)arow * 128 + quad * 8;
#pragma unroll
            for (int k0 = 0; k0 < 4; k0++) {
                float4 f0 = *(const float4*)(ap + k0 * 32);
                float4 f1 = *(const float4*)(ap + k0 * 32 + 4);
                half8 a;
                a[0]=(_Float16)f0.x; a[1]=(_Float16)f0.y; a[2]=(_Float16)f0.z; a[3]=(_Float16)f0.w;
                a[4]=(_Float16)f1.x; a[5]=(_Float16)f1.y; a[6]=(_Float16)f1.z; a[7]=(_Float16)f1.w;
                acur[k0] = a;
            }
        } else {
            const ushort_t* ap = A16 + (size_t)arow * 128 + quad * 8;
#pragma unroll
            for (int k0 = 0; k0 < 4; k0++) acur[k0] = *(const half8*)(ap + k0 * 32);
        }
    }

    while (true) {
        const int nt = tile + gridDim.x;
        const bool have_next = nt < ntiles;
        if (have_next) {
            int arow = nt * 16 + l16;
            if (arow >= M) arow = M - 1;
            if (Af32) {
                const float* ap = Af32 + (size_t)arow * 128 + quad * 8;
#pragma unroll
                for (int k0 = 0; k0 < 4; k0++) {
                    float4 f0 = *(const float4*)(ap + k0 * 32);
                    float4 f1 = *(const float4*)(ap + k0 * 32 + 4);
                    half8 a;
                    a[0]=(_Float16)f0.x; a[1]=(_Float16)f0.y; a[2]=(_Float16)f0.z; a[3]=(_Float16)f0.w;
                    a[4]=(_Float16)f1.x; a[5]=(_Float16)f1.y; a[6]=(_Float16)f1.z; a[7]=(_Float16)f1.w;
                    anext[k0] = a;
                }
            } else {
                const ushort_t* ap = A16 + (size_t)arow * 128 + quad * 8;
#pragma unroll
                for (int k0 = 0; k0 < 4; k0++) anext[k0] = *(const half8*)(ap + k0 * 32);
            }
        }

        float4v acc[4];
        float4v z = {0.f, 0.f, 0.f, 0.f};
#pragma unroll
        for (int c = 0; c < 4; c++) acc[c] = z;
#pragma unroll
        for (int k0 = 0; k0 < 4; k0++)
#pragma unroll
            for (int c = 0; c < 4; c++)
                acc[c] = __builtin_amdgcn_mfma_f32_16x16x32_f16(acur[k0], bf[c][k0], acc[c], 0, 0, 0);

        // epilogue — C/D: col=lane&15, row=quad*4+reg. acc[c][r] = memory col mcol+c.
        // For mode 1 the branch below is WAVE-UNIFORM (colbase is a multiple of 64).
        const int rowb = tile * 16 + quad * 4;
#pragma unroll
        for (int r = 0; r < 4; r++) {
            const int row = rowb + r;
            if (row < M) {
                const float v0 = acc[0][r] + bv.x;
                const float v1 = acc[1][r] + bv.y;
                const float v2 = acc[2][r] + bv.z;
                const float v3 = acc[3][r] + bv.w;
                if (mode == 0) {
                    uint2 u; u.x = pkrtz(v0, v1); u.y = pkrtz(v2, v3);
                    *(uint2*)(h16 + (size_t)row * 128 + mcol) = u;
                } else if (mcol < 256) {
                    uint2 u; u.x = pkrtz(v0, v1); u.y = pkrtz(v2, v3);
                    *(uint2*)(seed16 + (size_t)row * 256 + mcol) = u;
                } else {
                    // pack 4 values (gs0,sv0,gs1,sv1) as fp8 e4m3 into one dword
                    uint_t pk8 = (uint_t)__builtin_amdgcn_cvt_pk_fp8_f32(v0, v1, 0, false);
                    pk8 = (uint_t)__builtin_amdgcn_cvt_pk_fp8_f32(v2, v3, (int)pk8, true);
                    *(uint_t*)(gsv8 + (size_t)row * 256 + (mcol - 256)) = pk8;
                }
            }
        }

        if (!have_next) break;
#pragma unroll
        for (int k0 = 0; k0 < 4; k0++) acur[k0] = anext[k0];
        tile = nt;
    }
}

// ------------------------------------------------------------------
// R11: single fused setup kernel — wembed panel + wcat panel + bcat +
// hagg zeroing in one launch (was 2 kernels + 1 memset).
// Panel permutation: slot p (within 64-col group) = c*16+l16 feeds
// memory col m = 4*l16+c.
// Index space:
//   t in [0, 16384)                     : wembed
//   t in [16384, 16384+262144)          : wcat + bcat
//   t in [.., +32768)                   : hagg = 0
// ------------------------------------------------------------------
#define T_WE   (128 * 128)
#define T_WC   (NLAYERS * 512 * 128)
#define T_HAGG (NGRAPH * 128)

__global__ __launch_bounds__(256) void build_all(
    const float* __restrict__ We,
    const float* __restrict__ Wg, const float* __restrict__ Ws,
    const float* __restrict__ Wr, const float* __restrict__ bg,
    const float* __restrict__ bs, const float* __restrict__ br,
    ushort_t* __restrict__ wet, ushort_t* __restrict__ wct,
    float* __restrict__ bcat, float* __restrict__ hagg)
{
    int t = blockIdx.x * blockDim.x + threadIdx.x;
    if (t < T_WE) {
        int p = t >> 7, k = t & 127;
        int w = p >> 6, rem = p & 63, c = rem >> 4, l16 = rem & 15;
        int m = w * 64 + 4 * l16 + c;
        wet[t] = f2h(We[k * 128 + m]);
        return;
    }
    t -= T_WE;
    if (t < T_WC) {
        int l = t >> 16;
        int rm = t & 65535;
        int p = rm >> 7;
        int k = rm & 127;
        int w = p >> 6, rem = p & 63, c = rem >> 4, l16 = rem & 15;
        int m = w * 64 + 4 * l16 + c;
        const float NL2E = -1.44269504088896f;
        float v, b;
        if (m < 256) {
            int j = m >> 1;
            if ((m & 1) == 0) { v = NL2E * Wg[l * 32768 + k * 128 + j]; b = NL2E * bg[l * 128 + j]; }
            else              { v = Wr[l * 16384 + k * 128 + j];        b = br[l * 128 + j]; }
        } else {
            int j = (m - 256) >> 1;
            if ((m & 1) == 0) { v = NL2E * Wg[l * 32768 + (128 + k) * 128 + j]; b = 0.f; }
            else              { v = Ws[l * 16384 + k * 128 + j];               b = bs[l * 128 + j]; }
        }
        wct[t] = f2h(v);
        if (k == 0) bcat[l * 512 + m] = b;
        return;
    }
    t -= T_WC;
    if (t < T_HAGG) hagg[t] = 0.f;
}

// ------------------------------------------------------------------
// CSR build: histogram -> two-level scan -> scatter
// ------------------------------------------------------------------
__global__ __launch_bounds__(256) void hist_kernel(const int* __restrict__ ei,
                                                   int* __restrict__ cnt)
{
    int e = blockIdx.x * blockDim.x + threadIdx.x;
    if (e < N_EDGES) atomicAdd(&cnt[ei[N_EDGES + e]], 1);
}

__global__ __launch_bounds__(256) void scan_partial(const int* __restrict__ cnt,
                                                    int* __restrict__ part)
{
    __shared__ int ws[4];
    int tid = threadIdx.x, lane = tid & 63, wid = tid >> 6;
    int i = blockIdx.x * 256 + tid;
    int v = (i < N_NODES) ? cnt[i] : 0;
    int x = v;
#pragma unroll
    for (int ofs = 32; ofs > 0; ofs >>= 1) x += __shfl_down(x, ofs);
    if (lane == 0) ws[wid] = x;
    __syncthreads();
    if (tid == 0) part[blockIdx.x] = ws[0] + ws[1] + ws[2] + ws[3];
}

__global__ __launch_bounds__(256) void scan_root(const int* __restrict__ part,
                                                 int* __restrict__ partpre)
{
    __shared__ int ws[4];
    int tid = threadIdx.x, lane = tid & 63, wid = tid >> 6;
    int v = (tid < SCAN_BLOCKS) ? part[tid] : 0;
    int x = v;
#pragma unroll
    for (int ofs = 1; ofs < 64; ofs <<= 1) {
        int y = __shfl_up(x, ofs);
        if (lane >= ofs) x += y;
    }
    if (lane == 63) ws[wid] = x;
    __syncthreads();
    int add = 0;
    for (int w = 0; w < wid; w++) add += ws[w];
    if (tid < SCAN_BLOCKS) partpre[tid] = add + x - v;   // exclusive
}

__global__ __launch_bounds__(256) void scan_write(const int* __restrict__ cnt,
                                                  const int* __restrict__ partpre,
                                                  int* __restrict__ off)
{
    __shared__ int ws[4];
    int tid = threadIdx.x, lane = tid & 63, wid = tid >> 6;
    int i = blockIdx.x * 256 + tid;
    int v = (i < N_NODES) ? cnt[i] : 0;
    int x = v;
#pragma unroll
    for (int ofs = 1; ofs < 64; ofs <<= 1) {
        int y = __shfl_up(x, ofs);
        if (lane >= ofs) x += y;
    }
    if (lane == 63) ws[wid] = x;
    __syncthreads();
    int add = partpre[blockIdx.x];
    for (int w = 0; w < wid; w++) add += ws[w];
    if (i < N_NODES) off[i + 1] = add + x;
    if (i == 0) off[0] = 0;
}

__global__ __launch_bounds__(256) void scatter_kernel(const int* __restrict__ ei,
                                                      const int* __restrict__ off,
                                                      int* __restrict__ cur,
                                                      int* __restrict__ csr_send)
{
    int e = blockIdx.x * blockDim.x + threadIdx.x;
    if (e >= N_EDGES) return;
    int rec = ei[N_EDGES + e];
    int pos = off[rec] + atomicAdd(&cur[rec], 1);
    csr_send[pos] = ei[e];
}

// ------------------------------------------------------------------
// Node-centric aggregation + fused residual update (R9 champion,
// unchanged): 1 wave/node, 8/4/2/1 batched gather, fp8 e4m3 payload
// (256B/edge), fp16 seed, LDS pre-reduce pool on last layer.
// ------------------------------------------------------------------
__device__ __forceinline__ float sig_msg(float gpre, float sv) {
    // gpre = gr' + gs' (pre-scaled by -log2e): sigmoid = rcp(1+exp2(gpre))
    float e = __builtin_amdgcn_exp2f(gpre);
    return sv * __builtin_amdgcn_rcpf(1.f + e);
}

__global__ __launch_bounds__(256) void agg_kernel(
    const int* __restrict__ off, const int* __restrict__ csr_send,
    const ushort_t* __restrict__ seed16, const uchar_t* __restrict__ gsv8,
    ushort_t* __restrict__ h16,
    float* __restrict__ hagg, const int* __restrict__ batch)
{
    __shared__ float lred[4][128];
    __shared__ int lg[4];

    const int wave = threadIdx.x >> 6, lane = threadIdx.x & 63;
    const int n = blockIdx.x * 4 + wave;
    // N_NODES % 4 == 0, grid = N/4: every wave valid; no divergence
    // around __syncthreads below.

    ulong_t seed = *(const ulong_t*)(seed16 + (size_t)n * 256 + 4 * lane);
    // hoist the residual read so it's in flight under the gather loop
    uint_t hp = *(const uint_t*)(h16 + (size_t)n * 128 + 2 * lane);

    float gr0  = h2f((ushort_t)(seed & 0xffff));
    float acc0 = h2f((ushort_t)((seed >> 16) & 0xffff));
    float gr1  = h2f((ushort_t)((seed >> 32) & 0xffff));
    float acc1 = h2f((ushort_t)(seed >> 48));

    const uchar_t* gbase = gsv8 + 4 * lane;

    int p  = off[n];
    int p1 = off[n + 1];
    for (; p + 7 < p1; p += 8) {
        int s[8];
#pragma unroll
        for (int u = 0; u < 8; u++) s[u] = csr_send[p + u];
        uint_t q[8];
#pragma unroll
        for (int u = 0; u < 8; u++)
            q[u] = *(const uint_t*)(gbase + (size_t)s[u] * 256);
#pragma unroll
        for (int u = 0; u < 8; u++) {
            floatx2 a = __builtin_amdgcn_cvt_pk_f32_fp8(q[u], false);  // (gs0, sv0)
            floatx2 b = __builtin_amdgcn_cvt_pk_f32_fp8(q[u], true);   // (gs1, sv1)
            acc0 += sig_msg(gr0 + a.x, a.y);
            acc1 += sig_msg(gr1 + b.x, b.y);
        }
    }
    if (p + 3 < p1) {   // 4-wide tail batch (runs at most once)
        int s[4];
#pragma unroll
        for (int u = 0; u < 4; u++) s[u] = csr_send[p + u];
        uint_t q[4];
#pragma unroll
        for (int u = 0; u < 4; u++)
            q[u] = *(const uint_t*)(gbase + (size_t)s[u] * 256);
#pragma unroll
        for (int u = 0; u < 4; u++) {
            floatx2 a = __builtin_amdgcn_cvt_pk_f32_fp8(q[u], false);
            floatx2 b = __builtin_amdgcn_cvt_pk_f32_fp8(q[u], true);
            acc0 += sig_msg(gr0 + a.x, a.y);
            acc1 += sig_msg(gr1 + b.x, b.y);
        }
        p += 4;
    }
    if (p + 1 < p1) {   // 2-wide (runs at most once)
        int sa = csr_send[p], sb = csr_send[p + 1];
        uint_t qa = *(const uint_t*)(gbase + (size_t)sa * 256);
        uint_t qb = *(const uint_t*)(gbase + (size_t)sb * 256);
        floatx2 a0 = __builtin_amdgcn_cvt_pk_f32_fp8(qa, false);
        floatx2 a1 = __builtin_amdgcn_cvt_pk_f32_fp8(qa, true);
        floatx2 b0 = __builtin_amdgcn_cvt_pk_f32_fp8(qb, false);
        floatx2 b1 = __builtin_amdgcn_cvt_pk_f32_fp8(qb, true);
        acc0 += sig_msg(gr0 + a0.x, a0.y); acc1 += sig_msg(gr1 + a1.x, a1.y);
        acc0 += sig_msg(gr0 + b0.x, b0.y); acc1 += sig_msg(gr1 + b1.x, b1.y);
        p += 2;
    }
    if (p < p1) {
        int sa = csr_send[p];
        uint_t qa = *(const uint_t*)(gbase + (size_t)sa * 256);
        floatx2 a0 = __builtin_amdgcn_cvt_pk_f32_fp8(qa, false);
        floatx2 a1 = __builtin_amdgcn_cvt_pk_f32_fp8(qa, true);
        acc0 += sig_msg(gr0 + a0.x, a0.y); acc1 += sig_msg(gr1 + a1.x, a1.y);
    }

    float hx = h2f((ushort_t)(hp & 0xffff)) + fmaxf(acc0, 0.f);
    float hy = h2f((ushort_t)(hp >> 16))   + fmaxf(acc1, 0.f);

    if (hagg) {
        // fused global_add_pool with LDS block pre-reduction
        lred[wave][2 * lane]     = hx;
        lred[wave][2 * lane + 1] = hy;
        if (lane == 0) lg[wave] = batch[n];
        __syncthreads();
        if (wave == 0) {
            int gcur = lg[0];
            float a0 = lred[0][2 * lane], a1 = lred[0][2 * lane + 1];
#pragma unroll
            for (int w = 1; w < 4; w++) {
                const int gw = lg[w];
                const float b0 = lred[w][2 * lane], b1 = lred[w][2 * lane + 1];
                if (gw == gcur) { a0 += b0; a1 += b1; }
                else {
                    unsafeAtomicAdd(&hagg[(size_t)gcur * 128 + 2 * lane],     a0);
                    unsafeAtomicAdd(&hagg[(size_t)gcur * 128 + 2 * lane + 1], a1);
                    gcur = gw; a0 = b0; a1 = b1;
                }
            }
            unsafeAtomicAdd(&hagg[(size_t)gcur * 128 + 2 * lane],     a0);
            unsafeAtomicAdd(&hagg[(size_t)gcur * 128 + 2 * lane + 1], a1);
        }
    } else {
        *(uint_t*)(h16 + (size_t)n * 128 + 2 * lane) = pkrtz(hx, hy);
    }
}

// ------------------------------------------------------------------
// Head: out[g] = relu(hagg[g] @ W1 + b1) @ W2 + b2
// ------------------------------------------------------------------
__global__ __launch_bounds__(64) void head_kernel(
    const float* __restrict__ hagg, const float* __restrict__ W1,
    const float* __restrict__ b1, const float* __restrict__ W2,
    const float* __restrict__ b2, float* __restrict__ out)
{
    int g = blockIdx.x;
    int j = threadIdx.x;
    float acc = b1[j];
    for (int k = 0; k < 128; k++)
        acc += hagg[(size_t)g * 128 + k] * W1[k * 64 + j];
    float val = fmaxf(acc, 0.f) * W2[j];
#pragma unroll
    for (int off = 32; off > 0; off >>= 1)
        val += __shfl_down(val, off);
    if (j == 0) out[g] = val + b2[0];
}

// ------------------------------------------------------------------
extern "C" void kernel_launch(void* const* d_in, const int* in_sizes, int n_in,
                              void* d_out, int out_size, void* d_ws, size_t ws_size,
                              hipStream_t stream) {
    const float* h_in    = (const float*)d_in[0];
    const int*   ei      = (const int*)d_in[1];
    const int*   batch   = (const int*)d_in[2];
    const float* W_embed = (const float*)d_in[3];
    const float* b_embed = (const float*)d_in[4];
    const float* Wg      = (const float*)d_in[5];
    const float* bg      = (const float*)d_in[6];
    const float* Ws      = (const float*)d_in[7];
    const float* bs      = (const float*)d_in[8];
    const float* Wr      = (const float*)d_in[9];
    const float* br      = (const float*)d_in[10];
    const float* W1      = (const float*)d_in[11];
    const float* b1      = (const float*)d_in[12];
    const float* W2      = (const float*)d_in[13];
    const float* b2      = (const float*)d_in[14];
    float* out = (float*)d_out;

    // workspace layout (fp32, then fp16, then fp8, then ints)
    float* ws = (float*)d_ws;
    float*    hagg  = ws;                                    // G*128 f32
    float*    bcat  = hagg + NGRAPH * 128;                   // 4*512 f32
    ushort_t* h16   = (ushort_t*)(bcat + NLAYERS * 512);     // N*128 fp16
    ushort_t* seed16= h16 + (size_t)N_NODES * 128;           // N*256 fp16 (gr',r)
    ushort_t* wet   = seed16 + (size_t)N_NODES * 256;        // 128*128
    ushort_t* wct   = wet + 128 * 128;                       // 4*512*128
    uchar_t*  gsv8  = (uchar_t*)(wct + NLAYERS * 512 * 128); // N*256 fp8 (gs',sv)
    int* cnt      = (int*)(gsv8 + (size_t)N_NODES * 256);    // N
    int* cur      = cnt + N_NODES;                           // N
    int* off      = cur + N_NODES;                           // N+1
    int* csr_send = off + N_NODES + 1;                       // E
    int* part     = csr_send + N_EDGES;                      // SCAN_BLOCKS
    int* partpre  = part + SCAN_BLOCKS;                      // SCAN_BLOCKS

    // CSR build + fused setup (panels + bcat + hagg zero in one kernel)
    hipMemsetAsync(cnt, 0, (size_t)2 * N_NODES * sizeof(int), stream);
    hist_kernel<<<(N_EDGES + 255) / 256, 256, 0, stream>>>(ei, cnt);
    scan_partial<<<SCAN_BLOCKS, 256, 0, stream>>>(cnt, part);
    scan_root<<<1, 256, 0, stream>>>(part, partpre);
    scan_write<<<SCAN_BLOCKS, 256, 0, stream>>>(cnt, partpre, off);
    scatter_kernel<<<(N_EDGES + 255) / 256, 256, 0, stream>>>(ei, off, cur, csr_send);

    build_all<<<(T_WE + T_WC + T_HAGG + 255) / 256, 256, 0, stream>>>(
        W_embed, Wg, Ws, Wr, bg, bs, br, wet, wct, bcat, hagg);

    // embed: h16 = fp16(h_in @ W_embed + b_embed)  (reads fp32 A directly)
    {
        dim3 grid(768, 1);
        mfma_gemm_f16<<<grid, 128, 0, stream>>>(nullptr, h_in, wet, b_embed,
                                                N_NODES, 0, h16, nullptr, nullptr);
    }

    for (int l = 0; l < NLAYERS; l++) {
        dim3 grid(384, 2);
        mfma_gemm_f16<<<grid, 256, 0, stream>>>(h16, nullptr,
                                                wct + (size_t)l * 512 * 128,
                                                bcat + l * 512, N_NODES, 1,
                                                nullptr, seed16, gsv8);
        const bool last = (l == NLAYERS - 1);
        agg_kernel<<<N_NODES / 4, 256, 0, stream>>>(
            off, csr_send, seed16, gsv8, h16,
            last ? hagg : nullptr, last ? batch : nullptr);
    }

    head_kernel<<<NGRAPH, 64, 0, stream>>>(hagg, W1, b1, W2, b2, out);
}